// Round 16
// baseline (661.065 us; speedup 1.0000x reference)
//
#include <hip/hip_runtime.h>
#include <hip/hip_bf16.h>
#include <stdint.h>

#define STATE 512
#define PROJ 300
#define PPAD 320
#define BATSEQ 320
#define TE 327680            // 320*1024 edges
#define PSTR 328             // t2 tile stride (ushort) — spreads banks, keeps 16B align
#define TPB 10               // tiles per edge block

typedef __bf16 bf16x8 __attribute__((ext_vector_type(8)));
typedef float f32x4 __attribute__((ext_vector_type(4)));
typedef float f32x2 __attribute__((ext_vector_type(2)));
typedef long long i64;

__device__ inline unsigned short f2bf(float x) {
  unsigned u = __builtin_bit_cast(unsigned, x);
  unsigned r = u + 0x7fffu + ((u >> 16) & 1u);   // round-to-nearest-even
  return (unsigned short)(r >> 16);
}

// ---------------- prep: pack W1/W3 (bf16 MFMA B-fragments), W2-transposed (bf16),
// W2 in FP8 e4m3 B-fragments for the edge kernel, and padded biases ----------------
__global__ __launch_bounds__(256) void prep_kernel(
    const float* __restrict__ W1, const float* __restrict__ b1,
    const float* __restrict__ W2, const float* __restrict__ b2,
    const float* __restrict__ W3, const float* __restrict__ b3,
    unsigned short* __restrict__ w1p, unsigned short* __restrict__ w3p,
    unsigned short* __restrict__ w2tp, unsigned char* __restrict__ w2p8,
    float* __restrict__ b1p, float* __restrict__ b2p, float* __restrict__ b3p)
{
  int idx = blockIdx.x * 256 + threadIdx.x;
  const int WN = PPAD * STATE;                    // 163840
  if (idx < 2 * WN) {
    int which = idx / WN, r = idx % WN;
    int cs = r / 512, q = r % 512;                // cs = c*16+s
    int lane = q / 8, i = q % 8;
    int c = cs / 16, s = cs % 16;
    int p = c * 16 + (lane & 15);
    int k = s * 32 + (lane >> 4) * 8 + i;
    const float* W = (which == 0) ? W1 : W3;
    unsigned short* dst = (which == 0) ? w1p : w3p;
    float v = (p < PROJ) ? W[(size_t)p * STATE + k] : 0.0f;
    dst[r] = f2bf(v);
  } else if (idx < 3 * WN) {
    int r = idx - 2 * WN;
    int cs = r / 512, q = r % 512;
    int lane = q / 8, ii = q % 8;
    int ct = cs / 10, s2 = cs % 10;
    int p = s2 * 32 + (lane >> 4) * 8 + ii;
    int n = ct * 16 + (lane & 15);
    float v = (p < PROJ) ? W2[(size_t)p * STATE + n] : 0.0f;
    w2tp[r] = f2bf(v);
  } else if (idx < 4 * WN) {
    int r = idx - 3 * WN;                         // byte index
    int cs = r / 512, q = r % 512;
    int lane = q / 8, i = q % 8;
    int c = cs / 16, s = cs % 16;
    int p = c * 16 + (lane & 15);
    int k = s * 32 + (lane >> 4) * 8 + i;
    float v = (p < PROJ) ? W2[(size_t)p * STATE + k] : 0.0f;
    int pk = __builtin_amdgcn_cvt_pk_fp8_f32(v, 0.f, 0, 0);
    w2p8[r] = (unsigned char)(pk & 0xff);
  } else if (idx < 4 * WN + 3 * PPAD) {
    int r = idx - 4 * WN;
    int which = r / PPAD, p = r % PPAD;
    const float* B = (which == 0) ? b1 : ((which == 1) ? b2 : b3);
    float* dst = (which == 0) ? b1p : ((which == 1) ? b2p : b3p);
    dst[p] = (p < PROJ) ? B[p] : 0.0f;
  }
}

// ---------------- node kernel: one block per b.
// Phase A: f1 = W1*n + b1, f3' = W3*n + b3 - b2 (MFMA), closed-form
//   T_b = 32*sum(f1^2 + f3'^2) - 2*sum_p (sum_j f3')(sum_i f1)  -> pnode[b]
// Phase B: g1 = W2^T f1, g3 = W2^T f3' (MFMA via LDS bf16 tiles) -> f32 tables [b][32][512]
__global__ __launch_bounds__(256, 2) void node_kernel(
    const float* __restrict__ nodes,
    const unsigned short* __restrict__ w1p, const unsigned short* __restrict__ w3p,
    const unsigned short* __restrict__ w2tp,
    const float* __restrict__ b1p, const float* __restrict__ b2p,
    const float* __restrict__ b3p,
    float* __restrict__ g1t, float* __restrict__ g3t,
    double* __restrict__ pnode)
{
  __shared__ __align__(16) unsigned short tile[32 * 512];   // 32 KiB
  __shared__ __align__(16) unsigned short t2a[32 * PSTR];   // 20.5 KiB (f1, bf16)
  __shared__ __align__(16) unsigned short t2b[32 * PSTR];   // 20.5 KiB (f3', bf16)
  __shared__ float G1[PPAD], G3[PPAD];
  __shared__ double red[4];
  const int tid = threadIdx.x;
  const int wave = tid >> 6, lane = tid & 63;
  const int b = blockIdx.x;
  const float* src = nodes + (size_t)b * 32 * STATE;

  for (int t = tid; t < PPAD; t += 256) { G1[t] = 0.f; G3[t] = 0.f; }

  #pragma unroll
  for (int m = 0; m < 16; ++m) {
    int k = wave + 4 * m;
    int row = k >> 1;
    int fc = (k & 1) * 64 + lane;
    f32x4 v = *(const f32x4*)(src + row * STATE + fc * 4);
    unsigned lo = f2bf(v.x) | ((unsigned)f2bf(v.y) << 16);
    unsigned hi = f2bf(v.z) | ((unsigned)f2bf(v.w) << 16);
    unsigned long long pk = (unsigned long long)lo | ((unsigned long long)hi << 32);
    unsigned off = (unsigned)(row * 1024 + fc * 8) ^ (unsigned)((row & 7) << 4);
    *(unsigned long long*)((char*)tile + off) = pk;
  }
  __syncthreads();

  const int lrow = lane & 15, lk = lane >> 4;
  const int cbase = wave * 5;

  f32x4 af1[2][5], af3[2][5];
  #pragma unroll
  for (int rg = 0; rg < 2; ++rg)
    #pragma unroll
    for (int c = 0; c < 5; ++c) {
      af1[rg][c][0]=0.f; af1[rg][c][1]=0.f; af1[rg][c][2]=0.f; af1[rg][c][3]=0.f;
      af3[rg][c][0]=0.f; af3[rg][c][1]=0.f; af3[rg][c][2]=0.f; af3[rg][c][3]=0.f;
    }
  for (int s = 0; s < 16; ++s) {
    bf16x8 a[2];
    #pragma unroll
    for (int rg = 0; rg < 2; ++rg) {
      int row = rg * 16 + lrow;
      unsigned off = (unsigned)(row * 1024 + s * 64 + lk * 16) ^ (unsigned)((row & 7) << 4);
      a[rg] = *(const bf16x8*)((const char*)tile + off);
    }
    #pragma unroll
    for (int c = 0; c < 5; ++c) {
      size_t fo = ((size_t)(((cbase + c) * 16 + s) * 64 + lane)) * 8;
      bf16x8 bf1 = *(const bf16x8*)(w1p + fo);
      bf16x8 bf3 = *(const bf16x8*)(w3p + fo);
      #pragma unroll
      for (int rg = 0; rg < 2; ++rg) {
        af1[rg][c] = __builtin_amdgcn_mfma_f32_16x16x32_bf16(a[rg], bf1, af1[rg][c], 0, 0, 0);
        af3[rg][c] = __builtin_amdgcn_mfma_f32_16x16x32_bf16(a[rg], bf3, af3[rg][c], 0, 0, 0);
      }
    }
  }

  float sq = 0.f;
  #pragma unroll
  for (int rg = 0; rg < 2; ++rg)
    #pragma unroll
    for (int c = 0; c < 5; ++c) {
      int p = (cbase + c) * 16 + lrow;
      float bb1 = b1p[p], bb2 = b2p[p], bb3 = b3p[p];
      #pragma unroll
      for (int r = 0; r < 4; ++r) {
        int m = rg * 16 + lk * 4 + r;           // C/D row
        float v1 = af1[rg][c][r] + bb1;
        float v3 = af3[rg][c][r] + bb3 - bb2;
        t2a[m * PSTR + p] = f2bf(v1);
        t2b[m * PSTR + p] = f2bf(v3);
        sq += v1 * v1 + v3 * v3;
        atomicAdd(&G1[p], v1);
        atomicAdd(&G3[p], v3);
      }
    }
  __syncthreads();

  float s7 = 0.f;
  for (int t = tid; t < PPAD; t += 256) s7 += G3[t] * G1[t];
  float val = 32.f * sq - 2.f * s7;
  #pragma unroll
  for (int m = 32; m >= 1; m >>= 1) val += __shfl_xor(val, m, 64);
  if (lane == 0) red[wave] = (double)val;

  // ---- Phase B: g = W2^T f, two passes (f1 -> g1t, f3' -> g3t) ----
  for (int pass = 0; pass < 2; ++pass) {
    const unsigned short* t2 = pass ? t2b : t2a;
    float* gt = pass ? g3t : g1t;
    f32x4 acc2[2][8];
    #pragma unroll
    for (int rg = 0; rg < 2; ++rg)
      #pragma unroll
      for (int cc = 0; cc < 8; ++cc) { acc2[rg][cc][0]=0.f; acc2[rg][cc][1]=0.f; acc2[rg][cc][2]=0.f; acc2[rg][cc][3]=0.f; }
    for (int s2 = 0; s2 < 10; ++s2) {
      bf16x8 a[2];
      #pragma unroll
      for (int rg = 0; rg < 2; ++rg) {
        int mrow = rg * 16 + lrow;
        a[rg] = *(const bf16x8*)(t2 + mrow * PSTR + s2 * 32 + lk * 8);
      }
      #pragma unroll
      for (int cc = 0; cc < 8; ++cc) {
        int ct = wave * 8 + cc;
        bf16x8 bfr = *(const bf16x8*)(w2tp + ((size_t)((ct * 10 + s2) * 64 + lane)) * 8);
        #pragma unroll
        for (int rg = 0; rg < 2; ++rg)
          acc2[rg][cc] = __builtin_amdgcn_mfma_f32_16x16x32_bf16(a[rg], bfr, acc2[rg][cc], 0, 0, 0);
      }
    }
    #pragma unroll
    for (int rg = 0; rg < 2; ++rg)
      #pragma unroll
      for (int cc = 0; cc < 8; ++cc) {
        int n = (wave * 8 + cc) * 16 + lrow;
        #pragma unroll
        for (int r = 0; r < 4; ++r) {
          int mm = rg * 16 + lk * 4 + r;
          gt[((size_t)b * 32 + mm) * STATE + n] = acc2[rg][cc][r];
        }
      }
  }

  __syncthreads();
  if (tid == 0) pnode[b] = red[0] + red[1] + red[2] + red[3];
}

// ---------------- edge kernel (FP8, producer/consumer wave split): 512 threads,
// 2 blocks/CU. Waves 0-3 = producers: stream edges f32 -> fp8 -> LDS (double
// buffer) + sE.g1 fold. Waves 4-7 = consumers: R11's MFMA sum((W2 e)^2) +
// esumJ.g3 epilogue on the previous tile. One barrier per round: between
// consecutive barriers, producers stream tile r WHILE consumers eat tile r-1
// -> HBM busy in every window. 10 tiles per block, grid 512. ----------------
__global__ __launch_bounds__(512, 4) void edge_kernel(
    const float* __restrict__ edges, const unsigned char* __restrict__ w2p8,
    const float* __restrict__ g1t, const float* __restrict__ g3t,
    double* __restrict__ pedge)
{
  __shared__ __align__(16) unsigned char bufs[2][64 * 512];   // 2 x 32 KiB fp8
  __shared__ double redd[8][2];
  const int tid = threadIdx.x;
  const int wave = tid >> 6, lane = tid & 63;

  // XCD-chunked tile range: 64 blocks per XCD x 10 tiles = contiguous 640 tiles
  const int orig = blockIdx.x;                    // 0..511
  const int wg0 = (orig & 7) * 640 + (orig >> 3) * TPB;

  if (wave < 4) {
    // ---------------- producers: 256 threads ----------------
    const int fc = tid & 127;
    const int rhi = tid >> 7;                     // 0 or 1
    float crp = 0.f;
    for (int r = 0; r < TPB; ++r) {
      const int wg = wg0 + r;
      const int b = wg >> 4, q = wg & 15;
      const float* src = edges + ((size_t)b * 1024 + (size_t)q * 64) * STATE;
      const float* g1b = g1t + ((size_t)b * 32 + (size_t)q * 2) * STATE;
      unsigned char* buf = &bufs[r & 1][0];
      f32x4 sE0 = {0.f,0.f,0.f,0.f}, sE1 = {0.f,0.f,0.f,0.f};
      #pragma unroll 8
      for (int m = 0; m < 32; ++m) {
        int row = 2 * m + rhi;                    // 0..63
        f32x4 e = *(const f32x4*)(src + row * STATE + fc * 4);
        if (m < 16) sE0 += e; else sE1 += e;
        int pk = __builtin_amdgcn_cvt_pk_fp8_f32(e.x, e.y, 0, 0);
        pk = __builtin_amdgcn_cvt_pk_fp8_f32(e.z, e.w, pk, 1);
        unsigned off = (unsigned)(row * 512 + fc * 4) ^ (unsigned)((row & 7) << 3);
        *(int*)(buf + off) = pk;
      }
      f32x4 g1a = *(const f32x4*)(g1b + fc * 4);
      f32x4 g1c = *(const f32x4*)(g1b + STATE + fc * 4);
      crp -= sE0.x * g1a.x + sE0.y * g1a.y + sE0.z * g1a.z + sE0.w * g1a.w;
      crp -= sE1.x * g1c.x + sE1.y * g1c.y + sE1.z * g1c.z + sE1.w * g1c.w;
      __syncthreads();                            // barriers 1..10
    }
    #pragma unroll
    for (int m = 32; m >= 1; m >>= 1) crp += __shfl_xor(crp, m, 64);
    if (lane == 0) { redd[wave][0] = 0.0; redd[wave][1] = (double)crp; }
  } else {
    // ---------------- consumers: waves 4..7 ----------------
    const int wid = wave - 4;
    const int lrow = lane & 15, lk = lane >> 4;
    const int cb = wid * 5;
    const int tc = tid - 256;                     // 0..255
    float ssT = 0.f, crT = 0.f;
    __syncthreads();                              // barrier 1: tile 0 staged
    for (int r = 0; r < TPB; ++r) {
      const unsigned char* buf = &bufs[r & 1][0];
      const int wg = wg0 + r;
      const int b = wg >> 4;
      const float* g3b = g3t + (size_t)b * 32 * STATE;

      f32x4 acc[4][5];
      #pragma unroll
      for (int rg = 0; rg < 4; ++rg)
        #pragma unroll
        for (int c = 0; c < 5; ++c) { acc[rg][c][0]=0.f; acc[rg][c][1]=0.f; acc[rg][c][2]=0.f; acc[rg][c][3]=0.f; }
      for (int s = 0; s < 16; ++s) {
        i64 a[4];
        #pragma unroll
        for (int rg = 0; rg < 4; ++rg) {
          int row = rg * 16 + lrow;
          unsigned off = (unsigned)(row * 512 + s * 32 + lk * 8) ^ (unsigned)((row & 7) << 3);
          a[rg] = *(const i64*)(buf + off);
        }
        #pragma unroll
        for (int c = 0; c < 5; ++c) {
          i64 bfr = *(const i64*)(w2p8 + ((size_t)(((cb + c) * 16 + s) * 64 + lane)) * 8);
          #pragma unroll
          for (int rg = 0; rg < 4; ++rg)
            acc[rg][c] = __builtin_amdgcn_mfma_f32_16x16x32_fp8_fp8(a[rg], bfr, acc[rg][c], 0, 0, 0);
        }
      }
      #pragma unroll
      for (int rg = 0; rg < 4; ++rg)
        #pragma unroll
        for (int c = 0; c < 5; ++c)
          #pragma unroll
          for (int rr = 0; rr < 4; ++rr) ssT += acc[rg][c][rr] * acc[rg][c][rr];

      // esumJ . g3: thread = (j = tc>>3, s8 = tc&7); esumJ[j] = fp8 row j + row j+32
      {
        const int j = tc >> 3, s8 = tc & 7;
        const float* g3r = g3b + (size_t)j * STATE + s8 * 64;
        const unsigned sw = (unsigned)((j & 7) << 3);   // (j+32)&7 == j&7
        float part = 0.f;
        #pragma unroll
        for (int c = 0; c < 8; ++c) {
          unsigned o0 = (unsigned)(j * 512 + s8 * 64 + c * 8) ^ sw;
          unsigned o1 = (unsigned)((j + 32) * 512 + s8 * 64 + c * 8) ^ sw;
          i64 p0 = *(const i64*)(buf + o0);
          i64 p1 = *(const i64*)(buf + o1);
          int l0 = (int)(p0 & 0xffffffffll), h0 = (int)(((unsigned long long)p0) >> 32);
          int l1 = (int)(p1 & 0xffffffffll), h1 = (int)(((unsigned long long)p1) >> 32);
          f32x2 a0 = __builtin_amdgcn_cvt_pk_f32_fp8(l0, 0);
          f32x2 a1 = __builtin_amdgcn_cvt_pk_f32_fp8(l0, 1);
          f32x2 a2 = __builtin_amdgcn_cvt_pk_f32_fp8(h0, 0);
          f32x2 a3 = __builtin_amdgcn_cvt_pk_f32_fp8(h0, 1);
          f32x2 c0 = __builtin_amdgcn_cvt_pk_f32_fp8(l1, 0);
          f32x2 c1 = __builtin_amdgcn_cvt_pk_f32_fp8(l1, 1);
          f32x2 c2 = __builtin_amdgcn_cvt_pk_f32_fp8(h1, 0);
          f32x2 c3 = __builtin_amdgcn_cvt_pk_f32_fp8(h1, 1);
          f32x4 g0 = *(const f32x4*)(g3r + c * 8);
          f32x4 g1v = *(const f32x4*)(g3r + c * 8 + 4);
          part += (a0.x + c0.x) * g0.x + (a0.y + c0.y) * g0.y
                + (a1.x + c1.x) * g0.z + (a1.y + c1.y) * g0.w
                + (a2.x + c2.x) * g1v.x + (a2.y + c2.y) * g1v.y
                + (a3.x + c3.x) * g1v.z + (a3.y + c3.y) * g1v.w;
        }
        crT += part;
      }
      if (r < TPB - 1) __syncthreads();           // barriers 2..10
    }
    #pragma unroll
    for (int m = 32; m >= 1; m >>= 1) {
      ssT += __shfl_xor(ssT, m, 64);
      crT += __shfl_xor(crT, m, 64);
    }
    if (lane == 0) { redd[wave][0] = (double)ssT; redd[wave][1] = (double)crT; }
  }

  __syncthreads();                                // barrier 11 (both paths)
  if (tid == 0) {
    double sT = 0.0, cT = 0.0;
    #pragma unroll
    for (int w = 0; w < 8; ++w) { sT += redd[w][0]; cT += redd[w][1]; }
    pedge[orig] = sT - 2.0 * cT;
  }
}

// ---------------- final combine ----------------
__global__ __launch_bounds__(256) void final_kernel(
    const double* __restrict__ pedge, const double* __restrict__ pnode,
    const int* __restrict__ seqp, float* __restrict__ out)
{
  __shared__ double red[4];
  const int tid = threadIdx.x, wave = tid >> 6, lane = tid & 63;
  double v = 0.0;
  for (int t = tid; t < 512; t += 256) v += pedge[t];
  for (int t = tid; t < 320; t += 256) v += pnode[t];
  #pragma unroll
  for (int m = 32; m >= 1; m >>= 1) v += __shfl_xor(v, m, 64);
  if (lane == 0) red[wave] = v;
  __syncthreads();
  if (tid == 0) {
    double Total = red[0] + red[1] + red[2] + red[3];
    int seq = seqp[0];
    int batch = (seq > 0) ? (BATSEQ / seq) : 1;
    out[0] = (float)(Total / ((double)BATSEQ * (double)PROJ) / (double)batch);
  }
}

extern "C" void kernel_launch(void* const* d_in, const int* in_sizes, int n_in,
                              void* d_out, int out_size, void* d_ws, size_t ws_size,
                              hipStream_t stream)
{
  const float* nodes = (const float*)d_in[0];
  const float* edges = (const float*)d_in[1];
  const int*   seqp  = (const int*)d_in[4];
  const float* W1 = (const float*)d_in[5];
  const float* b1 = (const float*)d_in[6];
  const float* W2 = (const float*)d_in[7];
  const float* b2 = (const float*)d_in[8];
  const float* W3 = (const float*)d_in[9];
  const float* b3 = (const float*)d_in[10];

  char* ws = (char*)d_ws;
  unsigned short* w1p  = (unsigned short*)(ws + 0);         // 327680 B
  unsigned short* w3p  = (unsigned short*)(ws + 327680);    // 327680 B
  unsigned short* w2tp = (unsigned short*)(ws + 655360);    // 327680 B
  unsigned char*  w2p8 = (unsigned char*)(ws + 983040);     // 163840 B
  float* b1p = (float*)(ws + 1146880);
  float* b2p = (float*)(ws + 1148160);
  float* b3p = (float*)(ws + 1149440);
  float* g1t = (float*)(ws + 2097152);            // 20,971,520 B
  float* g3t = (float*)(ws + 23068672);           // 20,971,520 B
  double* pedge = (double*)(ws + 44040192);       // 512 doubles
  double* pnode = (double*)(ws + 44048384);       // 320 doubles

  prep_kernel<<<2564, 256, 0, stream>>>(W1, b1, W2, b2, W3, b3,
                                        w1p, w3p, w2tp, w2p8, b1p, b2p, b3p);
  node_kernel<<<320, 256, 0, stream>>>(nodes, w1p, w3p, w2tp, b1p, b2p, b3p,
                                       g1t, g3t, pnode);
  edge_kernel<<<512, 512, 0, stream>>>(edges, w2p8, g1t, g3t, pedge);
  final_kernel<<<1, 256, 0, stream>>>(pedge, pnode, seqp, (float*)d_out);
}

// Round 17
// 309.236 us; speedup vs baseline: 2.1377x; 2.1377x over previous
//
#include <hip/hip_runtime.h>
#include <hip/hip_bf16.h>
#include <stdint.h>

#define STATE 512
#define PROJ 300
#define PPAD 320
#define BATSEQ 320
#define TE 327680            // 320*1024 edges
#define PSTR 328             // t2 tile stride (ushort) — spreads banks, keeps 16B align

typedef __bf16 bf16x8 __attribute__((ext_vector_type(8)));
typedef float f32x4 __attribute__((ext_vector_type(4)));
typedef float f32x2 __attribute__((ext_vector_type(2)));
typedef long long i64;

__device__ inline unsigned short f2bf(float x) {
  unsigned u = __builtin_bit_cast(unsigned, x);
  unsigned r = u + 0x7fffu + ((u >> 16) & 1u);   // round-to-nearest-even
  return (unsigned short)(r >> 16);
}

// ---------------- prep: pack W1/W3 (bf16 MFMA B-fragments), W2-transposed (bf16),
// W2 in FP8 e4m3 B-fragments for the edge kernel, and padded biases ----------------
__global__ __launch_bounds__(256) void prep_kernel(
    const float* __restrict__ W1, const float* __restrict__ b1,
    const float* __restrict__ W2, const float* __restrict__ b2,
    const float* __restrict__ W3, const float* __restrict__ b3,
    unsigned short* __restrict__ w1p, unsigned short* __restrict__ w3p,
    unsigned short* __restrict__ w2tp, unsigned char* __restrict__ w2p8,
    float* __restrict__ b1p, float* __restrict__ b2p, float* __restrict__ b3p)
{
  int idx = blockIdx.x * 256 + threadIdx.x;
  const int WN = PPAD * STATE;                    // 163840
  if (idx < 2 * WN) {
    int which = idx / WN, r = idx % WN;
    int cs = r / 512, q = r % 512;                // cs = c*16+s
    int lane = q / 8, i = q % 8;
    int c = cs / 16, s = cs % 16;
    int p = c * 16 + (lane & 15);
    int k = s * 32 + (lane >> 4) * 8 + i;
    const float* W = (which == 0) ? W1 : W3;
    unsigned short* dst = (which == 0) ? w1p : w3p;
    float v = (p < PROJ) ? W[(size_t)p * STATE + k] : 0.0f;
    dst[r] = f2bf(v);
  } else if (idx < 3 * WN) {
    // w2tp: B-fragment for g-GEMM. value = W2[p][n], p = contraction (320, 10 s-steps),
    // n = state (512, 32 col-tiles). r = ((ct*10+s2)*64+lane)*8 + ii
    int r = idx - 2 * WN;
    int cs = r / 512, q = r % 512;
    int lane = q / 8, ii = q % 8;
    int ct = cs / 10, s2 = cs % 10;
    int p = s2 * 32 + (lane >> 4) * 8 + ii;
    int n = ct * 16 + (lane & 15);
    float v = (p < PROJ) ? W2[(size_t)p * STATE + n] : 0.0f;
    w2tp[r] = f2bf(v);
  } else if (idx < 4 * WN) {
    // w2p8: fp8 e4m3 B-fragment for the edge MFMA (16x16x32 fp8, 8 bytes/lane/step)
    int r = idx - 3 * WN;                         // byte index
    int cs = r / 512, q = r % 512;
    int lane = q / 8, i = q % 8;
    int c = cs / 16, s = cs % 16;
    int p = c * 16 + (lane & 15);
    int k = s * 32 + (lane >> 4) * 8 + i;
    float v = (p < PROJ) ? W2[(size_t)p * STATE + k] : 0.0f;
    int pk = __builtin_amdgcn_cvt_pk_fp8_f32(v, 0.f, 0, 0);
    w2p8[r] = (unsigned char)(pk & 0xff);
  } else if (idx < 4 * WN + 3 * PPAD) {
    int r = idx - 4 * WN;
    int which = r / PPAD, p = r % PPAD;
    const float* B = (which == 0) ? b1 : ((which == 1) ? b2 : b3);
    float* dst = (which == 0) ? b1p : ((which == 1) ? b2p : b3p);
    dst[p] = (p < PROJ) ? B[p] : 0.0f;
  }
}

// ---------------- node kernel: one block per b.
// Phase A: f1 = W1*n + b1, f3' = W3*n + b3 - b2 (MFMA), closed-form
//   T_b = 32*sum(f1^2 + f3'^2) - 2*sum_p (sum_j f3')(sum_i f1)  -> pnode[b]
// Phase B: g1 = W2^T f1, g3 = W2^T f3' (MFMA via LDS bf16 tiles) -> f32 tables [b][32][512]
__global__ __launch_bounds__(256, 2) void node_kernel(
    const float* __restrict__ nodes,
    const unsigned short* __restrict__ w1p, const unsigned short* __restrict__ w3p,
    const unsigned short* __restrict__ w2tp,
    const float* __restrict__ b1p, const float* __restrict__ b2p,
    const float* __restrict__ b3p,
    float* __restrict__ g1t, float* __restrict__ g3t,
    double* __restrict__ pnode)
{
  __shared__ __align__(16) unsigned short tile[32 * 512];   // 32 KiB
  __shared__ __align__(16) unsigned short t2a[32 * PSTR];   // 20.5 KiB (f1, bf16)
  __shared__ __align__(16) unsigned short t2b[32 * PSTR];   // 20.5 KiB (f3', bf16)
  __shared__ float G1[PPAD], G3[PPAD];
  __shared__ double red[4];
  const int tid = threadIdx.x;
  const int wave = tid >> 6, lane = tid & 63;
  const int b = blockIdx.x;
  const float* src = nodes + (size_t)b * 32 * STATE;

  for (int t = tid; t < PPAD; t += 256) { G1[t] = 0.f; G3[t] = 0.f; }

  // stage 32x512 f32 -> bf16 LDS, swizzle: byte ^= (row&7)<<4
  #pragma unroll
  for (int m = 0; m < 16; ++m) {
    int k = wave + 4 * m;
    int row = k >> 1;
    int fc = (k & 1) * 64 + lane;
    f32x4 v = *(const f32x4*)(src + row * STATE + fc * 4);
    unsigned lo = f2bf(v.x) | ((unsigned)f2bf(v.y) << 16);
    unsigned hi = f2bf(v.z) | ((unsigned)f2bf(v.w) << 16);
    unsigned long long pk = (unsigned long long)lo | ((unsigned long long)hi << 32);
    unsigned off = (unsigned)(row * 1024 + fc * 8) ^ (unsigned)((row & 7) << 4);
    *(unsigned long long*)((char*)tile + off) = pk;
  }
  __syncthreads();

  const int lrow = lane & 15, lk = lane >> 4;
  const int cbase = wave * 5;

  f32x4 af1[2][5], af3[2][5];
  #pragma unroll
  for (int rg = 0; rg < 2; ++rg)
    #pragma unroll
    for (int c = 0; c < 5; ++c) {
      af1[rg][c][0]=0.f; af1[rg][c][1]=0.f; af1[rg][c][2]=0.f; af1[rg][c][3]=0.f;
      af3[rg][c][0]=0.f; af3[rg][c][1]=0.f; af3[rg][c][2]=0.f; af3[rg][c][3]=0.f;
    }
  for (int s = 0; s < 16; ++s) {
    bf16x8 a[2];
    #pragma unroll
    for (int rg = 0; rg < 2; ++rg) {
      int row = rg * 16 + lrow;
      unsigned off = (unsigned)(row * 1024 + s * 64 + lk * 16) ^ (unsigned)((row & 7) << 4);
      a[rg] = *(const bf16x8*)((const char*)tile + off);
    }
    #pragma unroll
    for (int c = 0; c < 5; ++c) {
      size_t fo = ((size_t)(((cbase + c) * 16 + s) * 64 + lane)) * 8;
      bf16x8 bf1 = *(const bf16x8*)(w1p + fo);
      bf16x8 bf3 = *(const bf16x8*)(w3p + fo);
      #pragma unroll
      for (int rg = 0; rg < 2; ++rg) {
        af1[rg][c] = __builtin_amdgcn_mfma_f32_16x16x32_bf16(a[rg], bf1, af1[rg][c], 0, 0, 0);
        af3[rg][c] = __builtin_amdgcn_mfma_f32_16x16x32_bf16(a[rg], bf3, af3[rg][c], 0, 0, 0);
      }
    }
  }

  float sq = 0.f;
  #pragma unroll
  for (int rg = 0; rg < 2; ++rg)
    #pragma unroll
    for (int c = 0; c < 5; ++c) {
      int p = (cbase + c) * 16 + lrow;
      float bb1 = b1p[p], bb2 = b2p[p], bb3 = b3p[p];
      #pragma unroll
      for (int r = 0; r < 4; ++r) {
        int m = rg * 16 + lk * 4 + r;           // C/D row
        float v1 = af1[rg][c][r] + bb1;
        float v3 = af3[rg][c][r] + bb3 - bb2;
        t2a[m * PSTR + p] = f2bf(v1);
        t2b[m * PSTR + p] = f2bf(v3);
        sq += v1 * v1 + v3 * v3;
        atomicAdd(&G1[p], v1);
        atomicAdd(&G3[p], v3);
      }
    }
  __syncthreads();

  float s7 = 0.f;
  for (int t = tid; t < PPAD; t += 256) s7 += G3[t] * G1[t];
  float val = 32.f * sq - 2.f * s7;
  #pragma unroll
  for (int m = 32; m >= 1; m >>= 1) val += __shfl_xor(val, m, 64);
  if (lane == 0) red[wave] = (double)val;

  // ---- Phase B: g = W2^T f, two passes (f1 -> g1t, f3' -> g3t) ----
  for (int pass = 0; pass < 2; ++pass) {
    const unsigned short* t2 = pass ? t2b : t2a;
    float* gt = pass ? g3t : g1t;
    f32x4 acc2[2][8];
    #pragma unroll
    for (int rg = 0; rg < 2; ++rg)
      #pragma unroll
      for (int cc = 0; cc < 8; ++cc) { acc2[rg][cc][0]=0.f; acc2[rg][cc][1]=0.f; acc2[rg][cc][2]=0.f; acc2[rg][cc][3]=0.f; }
    for (int s2 = 0; s2 < 10; ++s2) {
      bf16x8 a[2];
      #pragma unroll
      for (int rg = 0; rg < 2; ++rg) {
        int mrow = rg * 16 + lrow;
        a[rg] = *(const bf16x8*)(t2 + mrow * PSTR + s2 * 32 + lk * 8);
      }
      #pragma unroll
      for (int cc = 0; cc < 8; ++cc) {
        int ct = wave * 8 + cc;
        bf16x8 bfr = *(const bf16x8*)(w2tp + ((size_t)((ct * 10 + s2) * 64 + lane)) * 8);
        #pragma unroll
        for (int rg = 0; rg < 2; ++rg)
          acc2[rg][cc] = __builtin_amdgcn_mfma_f32_16x16x32_bf16(a[rg], bfr, acc2[rg][cc], 0, 0, 0);
      }
    }
    #pragma unroll
    for (int rg = 0; rg < 2; ++rg)
      #pragma unroll
      for (int cc = 0; cc < 8; ++cc) {
        int n = (wave * 8 + cc) * 16 + lrow;
        #pragma unroll
        for (int r = 0; r < 4; ++r) {
          int mm = rg * 16 + lk * 4 + r;
          gt[((size_t)b * 32 + mm) * STATE + n] = acc2[rg][cc][r];
        }
      }
  }

  __syncthreads();
  if (tid == 0) pnode[b] = red[0] + red[1] + red[2] + red[3];
}

// ---------------- edge kernel (FP8): block = (b, i-pair), 64 rows, 256 threads, 3 blocks/CU.
// Staging: edge f32 load -> fp8 pack (cvt_pk_fp8) -> 32KB LDS (XOR (row&7)<<3) + row-sum regs.
// Cross i-part: sE0/sE1 . g1[i0],g1[i1] (exact f32). Cross j-part: esumJ from fp8 LDS . g3.
// MFMA: fp8 16x16x32, pure sum((W2 e)^2) — position-free, layout-bijection-safe.
__global__ __launch_bounds__(256, 3) void edge_kernel(
    const float* __restrict__ edges, const unsigned char* __restrict__ w2p8,
    const float* __restrict__ g1t, const float* __restrict__ g3t,
    double* __restrict__ pedge)
{
  __shared__ __align__(16) unsigned char tile[64 * 512];   // 32 KiB fp8
  __shared__ double redd[4][2];
  const int tid = threadIdx.x;
  const int wave = tid >> 6, lane = tid & 63;

  // XCD-chunked swizzle: all 16 blocks of one b land on one XCD (5120 % 8 == 0)
  const int orig = blockIdx.x;
  const int wg = (orig & 7) * 640 + (orig >> 3);
  const int b = wg >> 4, q = wg & 15;          // rows q*64..q*64+63, i-pair {2q, 2q+1}
  const float* src = edges + ((size_t)b * 1024 + (size_t)q * 64) * STATE;
  const float* g3b = g3t + (size_t)b * 32 * STATE;
  const float* g1b = g1t + ((size_t)b * 32 + (size_t)q * 2) * STATE;

  // ---- staging: 64x512 f32 -> fp8 LDS + register row-sums.
  float cr = 0.f;
  f32x4 sE0 = {0.f, 0.f, 0.f, 0.f}, sE1 = {0.f, 0.f, 0.f, 0.f};
  const int fc = tid & 127;
  const int rhi = tid >> 7;
  #pragma unroll 16
  for (int m = 0; m < 32; ++m) {
    int row = 2 * m + rhi;                      // 0..63
    f32x4 e = *(const f32x4*)(src + row * STATE + fc * 4);
    if (m < 16) sE0 += e; else sE1 += e;
    int pk = __builtin_amdgcn_cvt_pk_fp8_f32(e.x, e.y, 0, 0);
    pk = __builtin_amdgcn_cvt_pk_fp8_f32(e.z, e.w, pk, 1);
    unsigned off = (unsigned)(row * 512 + fc * 4) ^ (unsigned)((row & 7) << 3);
    *(int*)(tile + off) = pk;
  }
  {
    f32x4 g1a = *(const f32x4*)(g1b + fc * 4);            // g1[i0]
    f32x4 g1c = *(const f32x4*)(g1b + STATE + fc * 4);    // g1[i1]
    cr -= sE0.x * g1a.x + sE0.y * g1a.y + sE0.z * g1a.z + sE0.w * g1a.w;
    cr -= sE1.x * g1c.x + sE1.y * g1c.y + sE1.z * g1c.z + sE1.w * g1c.w;
  }
  __syncthreads();

  // ---- MFMA fp8: 64 rows x 320 cols. wave owns cols wave*80..+80, all 64 rows.
  const int lrow = lane & 15, lk = lane >> 4;
  const int cb = wave * 5;
  f32x4 acc[4][5];
  #pragma unroll
  for (int rg = 0; rg < 4; ++rg)
    #pragma unroll
    for (int c = 0; c < 5; ++c) { acc[rg][c][0]=0.f; acc[rg][c][1]=0.f; acc[rg][c][2]=0.f; acc[rg][c][3]=0.f; }
  for (int s = 0; s < 16; ++s) {
    i64 a[4];
    #pragma unroll
    for (int rg = 0; rg < 4; ++rg) {
      int row = rg * 16 + lrow;
      unsigned off = (unsigned)(row * 512 + s * 32 + lk * 8) ^ (unsigned)((row & 7) << 3);
      a[rg] = *(const i64*)(tile + off);
    }
    #pragma unroll
    for (int c = 0; c < 5; ++c) {
      i64 bfr = *(const i64*)(w2p8 + ((size_t)(((cb + c) * 16 + s) * 64 + lane)) * 8);
      #pragma unroll
      for (int rg = 0; rg < 4; ++rg)
        acc[rg][c] = __builtin_amdgcn_mfma_f32_16x16x32_fp8_fp8(a[rg], bfr, acc[rg][c], 0, 0, 0);
    }
  }

  float ss = 0.f;
  #pragma unroll
  for (int rg = 0; rg < 4; ++rg)
    #pragma unroll
    for (int c = 0; c < 5; ++c)
      #pragma unroll
      for (int r = 0; r < 4; ++r) ss += acc[rg][c][r] * acc[rg][c][r];

  // ---- esumJ . g3 pass: thread = (j = tid>>3, s8 = tid&7), d = s8*64 + c*8 .. +7.
  // esumJ[j] = fp8 row j + row j+32 (unpacked), dot g3[b][j].
  {
    const int j = tid >> 3, s8 = tid & 7;
    const float* g3r = g3b + (size_t)j * STATE + s8 * 64;
    const unsigned sw = (unsigned)((j & 7) << 3);   // (j+32)&7 == j&7
    float part = 0.f;
    #pragma unroll
    for (int c = 0; c < 8; ++c) {
      unsigned o0 = (unsigned)(j * 512 + s8 * 64 + c * 8) ^ sw;
      unsigned o1 = (unsigned)((j + 32) * 512 + s8 * 64 + c * 8) ^ sw;
      i64 p0 = *(const i64*)(tile + o0);
      i64 p1 = *(const i64*)(tile + o1);
      int l0 = (int)(p0 & 0xffffffffll), h0 = (int)(((unsigned long long)p0) >> 32);
      int l1 = (int)(p1 & 0xffffffffll), h1 = (int)(((unsigned long long)p1) >> 32);
      f32x2 a0 = __builtin_amdgcn_cvt_pk_f32_fp8(l0, 0);
      f32x2 a1 = __builtin_amdgcn_cvt_pk_f32_fp8(l0, 1);
      f32x2 a2 = __builtin_amdgcn_cvt_pk_f32_fp8(h0, 0);
      f32x2 a3 = __builtin_amdgcn_cvt_pk_f32_fp8(h0, 1);
      f32x2 c0 = __builtin_amdgcn_cvt_pk_f32_fp8(l1, 0);
      f32x2 c1 = __builtin_amdgcn_cvt_pk_f32_fp8(l1, 1);
      f32x2 c2 = __builtin_amdgcn_cvt_pk_f32_fp8(h1, 0);
      f32x2 c3 = __builtin_amdgcn_cvt_pk_f32_fp8(h1, 1);
      f32x4 g0 = *(const f32x4*)(g3r + c * 8);
      f32x4 g1v = *(const f32x4*)(g3r + c * 8 + 4);
      part += (a0.x + c0.x) * g0.x + (a0.y + c0.y) * g0.y
            + (a1.x + c1.x) * g0.z + (a1.y + c1.y) * g0.w
            + (a2.x + c2.x) * g1v.x + (a2.y + c2.y) * g1v.y
            + (a3.x + c3.x) * g1v.z + (a3.y + c3.y) * g1v.w;
    }
    cr += part;
  }

  #pragma unroll
  for (int m = 32; m >= 1; m >>= 1) {
    ss += __shfl_xor(ss, m, 64);
    cr += __shfl_xor(cr, m, 64);
  }
  if (lane == 0) { redd[wave][0] = (double)ss; redd[wave][1] = (double)cr; }
  __syncthreads();
  if (tid == 0) {
    double sT = 0.0, cT = 0.0;
    #pragma unroll
    for (int w = 0; w < 4; ++w) { sT += redd[w][0]; cT += redd[w][1]; }
    pedge[wg] = sT - 2.0 * cT;
  }
}

// ---------------- final combine ----------------
__global__ __launch_bounds__(256) void final_kernel(
    const double* __restrict__ pedge, const double* __restrict__ pnode,
    const int* __restrict__ seqp, float* __restrict__ out)
{
  __shared__ double red[4];
  const int tid = threadIdx.x, wave = tid >> 6, lane = tid & 63;
  double v = 0.0;
  for (int t = tid; t < 5120; t += 256) v += pedge[t];
  for (int t = tid; t < 320; t += 256) v += pnode[t];
  #pragma unroll
  for (int m = 32; m >= 1; m >>= 1) v += __shfl_xor(v, m, 64);
  if (lane == 0) red[wave] = v;
  __syncthreads();
  if (tid == 0) {
    double Total = red[0] + red[1] + red[2] + red[3];
    int seq = seqp[0];
    int batch = (seq > 0) ? (BATSEQ / seq) : 1;
    out[0] = (float)(Total / ((double)BATSEQ * (double)PROJ) / (double)batch);
  }
}

extern "C" void kernel_launch(void* const* d_in, const int* in_sizes, int n_in,
                              void* d_out, int out_size, void* d_ws, size_t ws_size,
                              hipStream_t stream)
{
  const float* nodes = (const float*)d_in[0];
  const float* edges = (const float*)d_in[1];
  const int*   seqp  = (const int*)d_in[4];
  const float* W1 = (const float*)d_in[5];
  const float* b1 = (const float*)d_in[6];
  const float* W2 = (const float*)d_in[7];
  const float* b2 = (const float*)d_in[8];
  const float* W3 = (const float*)d_in[9];
  const float* b3 = (const float*)d_in[10];

  char* ws = (char*)d_ws;
  unsigned short* w1p  = (unsigned short*)(ws + 0);         // 327680 B
  unsigned short* w3p  = (unsigned short*)(ws + 327680);    // 327680 B
  unsigned short* w2tp = (unsigned short*)(ws + 655360);    // 327680 B
  unsigned char*  w2p8 = (unsigned char*)(ws + 983040);     // 163840 B
  float* b1p = (float*)(ws + 1146880);
  float* b2p = (float*)(ws + 1148160);
  float* b3p = (float*)(ws + 1149440);
  float* g1t = (float*)(ws + 2097152);            // 20,971,520 B
  float* g3t = (float*)(ws + 23068672);           // 20,971,520 B
  double* pedge = (double*)(ws + 44040192);       // 5120 doubles
  double* pnode = (double*)(ws + 44081152);       // 320 doubles

  prep_kernel<<<2564, 256, 0, stream>>>(W1, b1, W2, b2, W3, b3,
                                        w1p, w3p, w2tp, w2p8, b1p, b2p, b3p);
  node_kernel<<<320, 256, 0, stream>>>(nodes, w1p, w3p, w2tp, b1p, b2p, b3p,
                                       g1t, g3t, pnode);
  edge_kernel<<<5120, 256, 0, stream>>>(edges, w2p8, g1t, g3t, pedge);
  final_kernel<<<1, 256, 0, stream>>>(pedge, pnode, seqp, (float*)d_out);
}